// Round 17
// baseline (141.858 us; speedup 1.0000x reference)
//
#include <hip/hip_runtime.h>
#include <hip/hip_bf16.h>

// Problem constants
#define TT 2048
#define BB 2
#define DM 128
#define HH 8
#define DH 16
#define FFN_N 1024
#define ROWS (TT * BB)
#define EPS_LN 1e-5f
#define NC 8              // s-chunks
#define SC (TT / NC)      // 256
#define NQ32 (TT / 32)    // 64 q-tiles of 32 per (b,h)
#define NQP (TT / 64)     // 32 q-PAIRS per (b,h)
#define NBH (BB * HH)     // 16
#define VROWS 32          // Vt rows per bh (16 data + row16=ones + 15 pad)
#define PSTRIDE 544       // pacc floats per task: 17 rows x 32 q

typedef __attribute__((ext_vector_type(8))) short bf16x8;
typedef __attribute__((ext_vector_type(4))) short bf16x4v;
typedef __attribute__((ext_vector_type(4))) float f32x4;
typedef __attribute__((ext_vector_type(16))) float f32x16;

__device__ __forceinline__ short f2bf(float x) {
    __hip_bfloat16 h = __float2bfloat16(x);
    union { __hip_bfloat16 hh; short s; } u; u.hh = h; return u.s;
}

// ---------------------------------------------------------------------------
// Fused weight convert+transpose: 10 weights f32 [K][N] -> bf16 [N][K].
// Also initializes Vt row 16 (per bh) to 1.0 bf16 for the ones-column trick.
// ---------------------------------------------------------------------------
__global__ __launch_bounds__(256) void cvt_w_all(
    const float* w0, const float* w1, const float* w2, const float* w3,
    const float* w4, const float* w5, const float* w6, const float* w7,
    const float* w8, const float* w9,
    short* o0, short* o1, short* o2, short* o3,
    short* o4, short* o5, short* o6, short* o7,
    short* o8, short* o9,
    short* vt1, short* vt2)
{
    // ones-row init: 2 tensors x NBH x TT = 65536 writes
    {
        const int id = blockIdx.x * 256 + threadIdx.x;
        if (id < 2 * NBH * TT) {
            const int sel = id / (NBH * TT);
            const int rem = id % (NBH * TT);
            const int bh = rem / TT, t = rem % TT;
            short* p = sel ? vt2 : vt1;
            p[((size_t)bh * VROWS + 16) * TT + t] = (short)0x3F80;
        }
    }

    const float* srcs[10] = {w0, w1, w2, w3, w4, w5, w6, w7, w8, w9};
    short* dsts[10] = {o0, o1, o2, o3, o4, o5, o6, o7, o8, o9};
    const int bx = blockIdx.x;
    int wi, tile, K, N;
    if (bx < 128)      { wi = bx >> 4; tile = bx & 15;  K = 128;  N = 128;  }
    else if (bx < 256) { wi = 8;       tile = bx - 128; K = 128;  N = 1024; }
    else               { wi = 9;       tile = bx - 256; K = 1024; N = 128;  }
    const float* src = srcs[wi];
    short* dst = dsts[wi];
    const int ntx = N >> 5;
    const int k0 = (tile / ntx) << 5;
    const int n0 = (tile % ntx) << 5;

    __shared__ float sm[32][33];
    const int j = threadIdx.x & 31;
    const int i0 = threadIdx.x >> 5;
    #pragma unroll
    for (int p = 0; p < 4; ++p) {
        const int ii = i0 + p * 8;
        sm[ii][j] = src[(size_t)(k0 + ii) * N + n0 + j];
    }
    __syncthreads();
    #pragma unroll
    for (int p = 0; p < 4; ++p) {
        const int ii = i0 + p * 8;
        dst[(size_t)(n0 + ii) * K + k0 + j] = f2bf(sm[j][ii]);
    }
}

// ---------------------------------------------------------------------------
// Fused QKV projection, 4 src-planes for occupancy (2 blocks/CU):
// z0: x -> Q,K_sa   z1: x -> V_sa   z2: enc -> K_ca   z3: enc -> V_ca
// f32 activations in (inline cvt), packed bf16 out (layouts verified r7).
// V^T rows stride VROWS=32 per bh (rows 0..15 written; row 16 = ones).
// ---------------------------------------------------------------------------
__global__ __launch_bounds__(256) void qkv_fused(
    const float* __restrict__ x, const float* __restrict__ enc,
    const short* __restrict__ W0, const short* __restrict__ W1, const short* __restrict__ W2,
    const short* __restrict__ W3, const short* __restrict__ W4,
    const float* __restrict__ B0, const float* __restrict__ B1, const float* __restrict__ B2,
    const float* __restrict__ B3, const float* __restrict__ B4,
    short* __restrict__ O0, short* __restrict__ O1, short* __restrict__ O2,
    short* __restrict__ O3, short* __restrict__ O4, float s0)
{
    const int zp = blockIdx.z;
    const float* A = (zp <= 1) ? x : enc;
    const int nw = (zp == 0) ? 2 : 1;
    const int zbase = (zp == 0) ? 0 : (zp == 1) ? 2 : (zp == 2) ? 3 : 4;
    const int K = DM, N = DM;

    const int tid = threadIdx.x;
    const int w = tid >> 6, lane = tid & 63;
    const int wm = w >> 1, wn = w & 1;
    const int g = lane >> 4, qi = lane & 15;
    const int bm = blockIdx.y * 64 + wm * 32;
    const int bn = blockIdx.x * 64 + wn * 32;

    for (int wsel = 0; wsel < nw; ++wsel) {
        const int z = zbase + wsel;
        const short* Wt = (z == 0) ? W0 : (z == 1) ? W1 : (z == 2) ? W2 : (z == 3) ? W3 : W4;
        const float* bias = (z == 0) ? B0 : (z == 1) ? B1 : (z == 2) ? B2 : (z == 3) ? B3 : B4;
        short* out = (z == 0) ? O0 : (z == 1) ? O1 : (z == 2) ? O2 : (z == 3) ? O3 : O4;
        const float scale = (z == 0) ? s0 : 1.f;
        const int vmode = (z == 2 || z == 4);

        f32x4 acc[2][2];
        #pragma unroll
        for (int a = 0; a < 2; ++a)
            #pragma unroll
            for (int b = 0; b < 2; ++b) acc[a][b] = (f32x4){0.f, 0.f, 0.f, 0.f};

        for (int k0 = 0; k0 < K; k0 += 32) {
            bf16x8 af[2], bf[2];
            #pragma unroll
            for (int fm = 0; fm < 2; ++fm) {
                const float* p = A + (size_t)(bm + fm * 16 + qi) * K + k0 + g * 4;
                float4 lo = *(const float4*)p;
                float4 hi = *(const float4*)(p + 16);
                af[fm][0] = f2bf(lo.x); af[fm][1] = f2bf(lo.y); af[fm][2] = f2bf(lo.z); af[fm][3] = f2bf(lo.w);
                af[fm][4] = f2bf(hi.x); af[fm][5] = f2bf(hi.y); af[fm][6] = f2bf(hi.z); af[fm][7] = f2bf(hi.w);
            }
            #pragma unroll
            for (int fn = 0; fn < 2; ++fn) {
                const short* p = Wt + (size_t)(bn + fn * 16 + qi) * K + k0 + g * 4;
                bf16x4v lo = *(const bf16x4v*)p;
                bf16x4v hi = *(const bf16x4v*)(p + 16);
                bf[fn][0] = lo[0]; bf[fn][1] = lo[1]; bf[fn][2] = lo[2]; bf[fn][3] = lo[3];
                bf[fn][4] = hi[0]; bf[fn][5] = hi[1]; bf[fn][6] = hi[2]; bf[fn][7] = hi[3];
            }
            #pragma unroll
            for (int fm = 0; fm < 2; ++fm)
                #pragma unroll
                for (int fn = 0; fn < 2; ++fn)
                    acc[fm][fn] = __builtin_amdgcn_mfma_f32_16x16x32_bf16(
                        af[fm], bf[fn], acc[fm][fn], 0, 0, 0);
        }

        #pragma unroll
        for (int fm = 0; fm < 2; ++fm)
            #pragma unroll
            for (int fn = 0; fn < 2; ++fn)
                #pragma unroll
                for (int r = 0; r < 4; ++r) {
                    const int m = bm + fm * 16 + g * 4 + r;
                    const int n = bn + fn * 16 + qi;
                    const float v = (acc[fm][fn][r] + bias[n]) * scale;
                    const int t = m >> 1, bz = m & 1, hH = n >> 4, d = n & 15;
                    size_t idx;
                    if (!vmode) {
                        const int dp = ((d >> 2) & 1) * 8 + (d & 3) + ((d >> 3) & 1) * 4;
                        idx = ((size_t)(bz * HH + hH) * TT + t) * DH + dp;
                    } else {
                        const int u = t & 15;
                        const int tp = (t & ~15) | (((u >> 2) & 1) * 8 + (u & 3) + ((u >> 3) & 1) * 4);
                        idx = ((size_t)(bz * HH + hH) * VROWS + d) * TT + tp;
                    }
                    out[idx] = f2bf(v);
                }
    }
}

// ---------------------------------------------------------------------------
// Flash attention PARTIAL. 32x32x16 MFMA, static-max softmax, exp2-folded,
// paired q-tiles, ones-column trick (Vt row 16 = 1.0 -> PV col 16 = L).
// launch_bounds(256,6): post-ones-trick live VGPRs ~80 fit the 85 cap ->
// 6 waves/SIMD for the latency-bound exp2/cvt chain.
// ---------------------------------------------------------------------------
template<int CAUSAL>
__global__ __launch_bounds__(256, 6) void attn_part(
    const short* __restrict__ Qh, const short* __restrict__ Kh,
    const short* __restrict__ Vt, float* __restrict__ pacc)
{
    const int wv = threadIdx.x >> 6;
    const int lane = threadIdx.x & 63;
    const int tsk = blockIdx.x * 4 + wv;        // ((bh*NQP + qp)*NC + c)
    const int bh = tsk >> 8;                    // /(NQP*NC)=256
    const int rr = tsk & 255;
    const int c = rr & (NC - 1);
    const int qp0 = rr >> 3;
    const int qp = (qp0 * 13 + c * 5) & (NQP - 1);   // bijective scramble
    const int qtA = qp * 64;
    const int qtB = qtA + 32;
    const int start = c * SC;
    const int send = CAUSAL ? min(start + SC, qtB + 32) : (start + SC);
    if (CAUSAL && start >= send) return;

    const int q = lane & 31;
    const int h = lane >> 5;

    const bf16x8 qf1 = *(const bf16x8*)(Qh + ((size_t)bh * TT + qtA + q) * DH + h * 8);
    const bf16x8 qf2 = *(const bf16x8*)(Qh + ((size_t)bh * TT + qtB + q) * DH + h * 8);

    f32x16 acc1, acc2;
    #pragma unroll
    for (int i = 0; i < 16; ++i) { acc1[i] = 0.f; acc2[i] = 0.f; }

    for (int sb = start; sb < send; sb += 32) {
        const bf16x8 kf = *(const bf16x8*)(Kh + ((size_t)bh * TT + sb + q) * DH + h * 8);
        f32x16 z;
        #pragma unroll
        for (int i = 0; i < 16; ++i) z[i] = 0.f;
        f32x16 s1 = __builtin_amdgcn_mfma_f32_32x32x16_bf16(kf, qf1, z, 0, 0, 0);
        f32x16 s2 = __builtin_amdgcn_mfma_f32_32x32x16_bf16(kf, qf2, z, 0, 0, 0);

        if (CAUSAL && (sb + 31 > qtA)) {
            #pragma unroll
            for (int r = 0; r < 16; ++r) {
                const int s_glob = sb + (r & 3) + 8 * (r >> 2) + 4 * h;
                if (s_glob > qtA + q) s1[r] = -1.0e30f;
                if (s_glob > qtB + q) s2[r] = -1.0e30f;
            }
        }

        #pragma unroll
        for (int i = 0; i < 16; ++i) {
            s1[i] = exp2f(s1[i]);
            s2[i] = exp2f(s2[i]);
        }

        #pragma unroll
        for (int j = 0; j < 2; ++j) {
            bf16x8 pf1, pf2;
            #pragma unroll
            for (int e = 0; e < 8; ++e) { pf1[e] = f2bf(s1[8 * j + e]); pf2[e] = f2bf(s2[8 * j + e]); }
            const bf16x8 vf = *(const bf16x8*)(Vt + ((size_t)bh * VROWS + q) * TT + sb + 16 * j + h * 8);
            acc1 = __builtin_amdgcn_mfma_f32_32x32x16_bf16(pf1, vf, acc1, 0, 0, 0);
            acc2 = __builtin_amdgcn_mfma_f32_32x32x16_bf16(pf2, vf, acc2, 0, 0, 0);
        }
    }

    const size_t tA = ((size_t)bh * NQ32 + qp * 2) * NC + c;
    const size_t tB = ((size_t)bh * NQ32 + qp * 2 + 1) * NC + c;
    const int d = q;
    if (d < 17) {                     // rows 0..15 = O partials, row 16 = L
        float* pb1 = pacc + tA * PSTRIDE + (size_t)d * 32;
        float* pb2 = pacc + tB * PSTRIDE + (size_t)d * 32;
        *(f32x4*)(pb1 + 4 * h)      = (f32x4){acc1[0],  acc1[1],  acc1[2],  acc1[3]};
        *(f32x4*)(pb1 + 8 + 4 * h)  = (f32x4){acc1[4],  acc1[5],  acc1[6],  acc1[7]};
        *(f32x4*)(pb1 + 16 + 4 * h) = (f32x4){acc1[8],  acc1[9],  acc1[10], acc1[11]};
        *(f32x4*)(pb1 + 24 + 4 * h) = (f32x4){acc1[12], acc1[13], acc1[14], acc1[15]};
        *(f32x4*)(pb2 + 4 * h)      = (f32x4){acc2[0],  acc2[1],  acc2[2],  acc2[3]};
        *(f32x4*)(pb2 + 8 + 4 * h)  = (f32x4){acc2[4],  acc2[5],  acc2[6],  acc2[7]};
        *(f32x4*)(pb2 + 16 + 4 * h) = (f32x4){acc2[8],  acc2[9],  acc2[10], acc2[11]};
        *(f32x4*)(pb2 + 24 + 4 * h) = (f32x4){acc2[12], acc2[13], acc2[14], acc2[15]};
    }
}

// ---------------------------------------------------------------------------
// Flash attention MERGE (static-max: plain sums; L = pacc row 16).
// One wave per (bh, qt32).
// ---------------------------------------------------------------------------
__global__ __launch_bounds__(256) void attn_merge(
    const float* __restrict__ pacc, short* __restrict__ outb, int causal)
{
    const int wv = threadIdx.x >> 6;
    const int lane = threadIdx.x & 63;
    const int task2 = blockIdx.x * 4 + wv;    // bh*NQ32 + qt32
    const int qt32 = task2 & (NQ32 - 1);
    const int bh = task2 >> 6;
    const int bz = bh / HH, head = bh % HH;
    const int qt = qt32 * 32;
    const int q = lane & 31, h = lane >> 5;
    const int qp = qt32 >> 1;
    const int nc = causal ? min(NC, (qp * 64 + 64 + SC - 1) / SC) : NC;
    const size_t base = (size_t)task2 * NC;

    float L = 0.f;
    float o[8] = {0.f, 0.f, 0.f, 0.f, 0.f, 0.f, 0.f, 0.f};
    for (int c = 0; c < nc; ++c) {
        const float* pb = pacc + (base + c) * PSTRIDE;
        L += pb[16 * 32 + q];
        const float* pr = pb + (size_t)h * 8 * 32 + q;
        #pragma unroll
        for (int dd = 0; dd < 8; ++dd) o[dd] += pr[dd * 32];
    }

    const float inv = 1.f / L;
    short* op = outb + ((size_t)(qt + q) * BB + bz) * DM + head * DH + h * 8;
    bf16x8 ov;
    #pragma unroll
    for (int dd = 0; dd < 8; ++dd) ov[dd] = f2bf(o[dd] * inv);
    *(bf16x8*)op = ov;
}

// ---------------------------------------------------------------------------
// Fused GEMM(+bias+resid)+LayerNorm, 256 threads = 4 waves (r11-verified).
// QPROJ=1 additionally computes the cross-attn Q projection of the LN output.
// ---------------------------------------------------------------------------
template<int KSTEPS, int QPROJ>
__global__ __launch_bounds__(256) void lngemm(
    const short* __restrict__ A, const short* __restrict__ Wt,
    const float* __restrict__ bias, const float* __restrict__ resid,
    const float* __restrict__ lg, const float* __restrict__ lb,
    float* __restrict__ outF,
    const short* __restrict__ Wq, const float* __restrict__ bq,
    short* __restrict__ Oq, float qs)
{
    const int tid = threadIdx.x;
    const int w = tid >> 6;
    const int lane = tid & 63;
    const int ch = w & 1, kh = w >> 1;
    const int gq = lane >> 4, qi = lane & 15;
    const int m0 = blockIdx.x * 16;
    const int K = KSTEPS * 32;
    const int KH = KSTEPS / 2;

    __shared__ float part[16][130];
    __shared__ float smean[2][16], ssq[2][16];
    __shared__ short Alds[16][136];

    f32x4 acc[4];
    #pragma unroll
    for (int fn = 0; fn < 4; ++fn) acc[fn] = (f32x4){0.f, 0.f, 0.f, 0.f};

    for (int ks = kh * KH; ks < kh * KH + KH; ++ks) {
        const int k0 = ks * 32;
        bf16x8 af;
        {
            const short* p = A + (size_t)(m0 + qi) * K + k0 + gq * 4;
            bf16x4v lo = *(const bf16x4v*)p;
            bf16x4v hi = *(const bf16x4v*)(p + 16);
            af[0] = lo[0]; af[1] = lo[1]; af[2] = lo[2]; af[3] = lo[3];
            af[4] = hi[0]; af[5] = hi[1]; af[6] = hi[2]; af[7] = hi[3];
        }
        #pragma unroll
        for (int fn = 0; fn < 4; ++fn) {
            const short* p = Wt + (size_t)(ch * 64 + fn * 16 + qi) * K + k0 + gq * 4;
            bf16x4v lo = *(const bf16x4v*)p;
            bf16x4v hi = *(const bf16x4v*)(p + 16);
            bf16x8 bf;
            bf[0] = lo[0]; bf[1] = lo[1]; bf[2] = lo[2]; bf[3] = lo[3];
            bf[4] = hi[0]; bf[5] = hi[1]; bf[6] = hi[2]; bf[7] = hi[3];
            acc[fn] = __builtin_amdgcn_mfma_f32_16x16x32_bf16(af, bf, acc[fn], 0, 0, 0);
        }
    }

    if (kh == 1) {
        #pragma unroll
        for (int fn = 0; fn < 4; ++fn)
            #pragma unroll
            for (int r = 0; r < 4; ++r)
                part[gq * 4 + r][ch * 64 + fn * 16 + qi] = acc[fn][r];
    }
    __syncthreads();

    float vv[4][4];
    if (kh == 0) {
        #pragma unroll
        for (int fn = 0; fn < 4; ++fn) {
            const int n = ch * 64 + fn * 16 + qi;
            const float bn = bias[n];
            #pragma unroll
            for (int r = 0; r < 4; ++r) {
                const int m = m0 + gq * 4 + r;
                vv[fn][r] = acc[fn][r] + part[gq * 4 + r][n] + bn
                          + resid[(size_t)m * DM + n];
            }
        }
        float ps[4], pq[4];
        #pragma unroll
        for (int r = 0; r < 4; ++r) {
            float s = 0.f, q2 = 0.f;
            #pragma unroll
            for (int fn = 0; fn < 4; ++fn) { s += vv[fn][r]; q2 += vv[fn][r] * vv[fn][r]; }
            #pragma unroll
            for (int off = 1; off < 16; off <<= 1) {
                s += __shfl_xor(s, off);
                q2 += __shfl_xor(q2, off);
            }
            ps[r] = s; pq[r] = q2;
        }
        if (qi == 0) {
            #pragma unroll
            for (int r = 0; r < 4; ++r) {
                smean[ch][gq * 4 + r] = ps[r];
                ssq[ch][gq * 4 + r] = pq[r];
            }
        }
    }
    __syncthreads();

    if (kh == 0) {
        #pragma unroll
        for (int r = 0; r < 4; ++r) {
            const int row = gq * 4 + r;
            const int m = m0 + row;
            const float mean = (smean[0][row] + smean[1][row]) * (1.f / DM);
            const float var = (ssq[0][row] + ssq[1][row]) * (1.f / DM) - mean * mean;
            const float rstd = rsqrtf(var + EPS_LN);
            #pragma unroll
            for (int fn = 0; fn < 4; ++fn) {
                const int n = ch * 64 + fn * 16 + qi;
                const float val = (vv[fn][r] - mean) * rstd * lg[n] + lb[n];
                outF[(size_t)m * DM + n] = val;
                if (QPROJ) Alds[row][n] = f2bf(val);
            }
        }
    }

    if (QPROJ) {
        __syncthreads();
        f32x4 qacc[2];
        qacc[0] = (f32x4){0.f, 0.f, 0.f, 0.f};
        qacc[1] = (f32x4){0.f, 0.f, 0.f, 0.f};
        for (int ks = 0; ks < 4; ++ks) {
            const int k0 = ks * 32;
            bf16x8 af;
            {
                const short* p = &Alds[qi][k0 + gq * 4];
                af[0] = p[0]; af[1] = p[1]; af[2] = p[2]; af[3] = p[3];
                af[4] = p[16]; af[5] = p[17]; af[6] = p[18]; af[7] = p[19];
            }
            #pragma unroll
            for (int fn = 0; fn < 2; ++fn) {
                const short* p = Wq + (size_t)(w * 32 + fn * 16 + qi) * DM + k0 + gq * 4;
                bf16x4v lo = *(const bf16x4v*)p;
                bf16x4v hi = *(const bf16x4v*)(p + 16);
                bf16x8 bf;
                bf[0] = lo[0]; bf[1] = lo[1]; bf[2] = lo[2]; bf[3] = lo[3];
                bf[4] = hi[0]; bf[5] = hi[1]; bf[6] = hi[2]; bf[7] = hi[3];
                qacc[fn] = __builtin_amdgcn_mfma_f32_16x16x32_bf16(af, bf, qacc[fn], 0, 0, 0);
            }
        }
        #pragma unroll
        for (int fn = 0; fn < 2; ++fn)
            #pragma unroll
            for (int r = 0; r < 4; ++r) {
                const int m = m0 + gq * 4 + r;
                const int n = w * 32 + fn * 16 + qi;
                const float v = (qacc[fn][r] + bq[n]) * qs;
                const int t = m >> 1, bz = m & 1, hH = n >> 4, d = n & 15;
                const int dp = ((d >> 2) & 1) * 8 + (d & 3) + ((d >> 3) & 1) * 4;
                Oq[((size_t)(bz * HH + hH) * TT + t) * DH + dp] = f2bf(v);
            }
    }
}

// ---------------------------------------------------------------------------
// Fused FFN: fc1+gelu (-> LDS) + fc2 + LN3 -> out. Block = 16 rows, 512 thr.
// ---------------------------------------------------------------------------
__global__ __launch_bounds__(512) void ffn_fused(
    const float* __restrict__ Af,    // b6 f32 [ROWS][DM] (also the residual)
    const short* __restrict__ W1t, const float* __restrict__ b1,
    const short* __restrict__ W2t, const float* __restrict__ b2,
    const float* __restrict__ lg, const float* __restrict__ lb,
    float* __restrict__ outF)
{
    const int tid = threadIdx.x;
    const int w = tid >> 6, lane = tid & 63;
    const int gq = lane >> 4, qi = lane & 15;
    const int m0 = blockIdx.x * 16;

    __shared__ short hlds[16][1032];
    __shared__ float part[3][16][130];
    __shared__ float smean[2][16], ssq[2][16];

    // ---- phase 1: fc1 + gelu ----
    {
        f32x4 acc[8];
        #pragma unroll
        for (int fn = 0; fn < 8; ++fn) acc[fn] = (f32x4){0.f, 0.f, 0.f, 0.f};
        for (int ks = 0; ks < 4; ++ks) {
            const int k0 = ks * 32;
            bf16x8 af;
            {
                const float* p = Af + (size_t)(m0 + qi) * DM + k0 + gq * 4;
                float4 lo = *(const float4*)p;
                float4 hi = *(const float4*)(p + 16);
                af[0] = f2bf(lo.x); af[1] = f2bf(lo.y); af[2] = f2bf(lo.z); af[3] = f2bf(lo.w);
                af[4] = f2bf(hi.x); af[5] = f2bf(hi.y); af[6] = f2bf(hi.z); af[7] = f2bf(hi.w);
            }
            #pragma unroll
            for (int fn = 0; fn < 8; ++fn) {
                const short* p = W1t + (size_t)(w * 128 + fn * 16 + qi) * DM + k0 + gq * 4;
                bf16x4v lo = *(const bf16x4v*)p;
                bf16x4v hi = *(const bf16x4v*)(p + 16);
                bf16x8 bf;
                bf[0] = lo[0]; bf[1] = lo[1]; bf[2] = lo[2]; bf[3] = lo[3];
                bf[4] = hi[0]; bf[5] = hi[1]; bf[6] = hi[2]; bf[7] = hi[3];
                acc[fn] = __builtin_amdgcn_mfma_f32_16x16x32_bf16(af, bf, acc[fn], 0, 0, 0);
            }
        }
        #pragma unroll
        for (int fn = 0; fn < 8; ++fn) {
            const int n = w * 128 + fn * 16 + qi;
            const float bn = b1[n];
            #pragma unroll
            for (int r = 0; r < 4; ++r) {
                float v = acc[fn][r] + bn;
                v = 0.5f * v * (1.f + erff(v * 0.70710678118654752f));
                hlds[gq * 4 + r][n] = f2bf(v);
            }
        }
    }
    __syncthreads();

    // ---- phase 2: fc2 + LN3 ----
    const int ch = w & 1, kh = w >> 1;   // kh 0..3

    f32x4 acc2[4];
    #pragma unroll
    for (int fn = 0; fn < 4; ++fn) acc2[fn] = (f32x4){0.f, 0.f, 0.f, 0.f};

    for (int ks = kh * 8; ks < kh * 8 + 8; ++ks) {
        const int k0 = ks * 32;
        bf16x8 af;
        {
            const short* p = &hlds[qi][k0 + gq * 4];
            af[0] = p[0]; af[1] = p[1]; af[2] = p[2]; af[3] = p[3];
            af[4] = p[16]; af[5] = p[17]; af[6] = p[18]; af[7] = p[19];
        }
        #pragma unroll
        for (int fn = 0; fn < 4; ++fn) {
            const short* p = W2t + (size_t)(ch * 64 + fn * 16 + qi) * FFN_N + k0 + gq * 4;
            bf16x4v lo = *(const bf16x4v*)p;
            bf16x4v hi = *(const bf16x4v*)(p + 16);
            bf16x8 bf;
            bf[0] = lo[0]; bf[1] = lo[1]; bf[2] = lo[2]; bf[3] = lo[3];
            bf[4] = hi[0]; bf[5] = hi[1]; bf[6] = hi[2]; bf[7] = hi[3];
            acc2[fn] = __builtin_amdgcn_mfma_f32_16x16x32_bf16(af, bf, acc2[fn], 0, 0, 0);
        }
    }

    if (kh >= 1) {
        #pragma unroll
        for (int fn = 0; fn < 4; ++fn)
            #pragma unroll
            for (int r = 0; r < 4; ++r)
                part[kh - 1][gq * 4 + r][ch * 64 + fn * 16 + qi] = acc2[fn][r];
    }
    __syncthreads();

    float vv[4][4];
    if (kh == 0) {
        #pragma unroll
        for (int fn = 0; fn < 4; ++fn) {
            const int n = ch * 64 + fn * 16 + qi;
            const float bn = b2[n];
            #pragma unroll
            for (int r = 0; r < 4; ++r) {
                const int row = gq * 4 + r;
                const int m = m0 + row;
                vv[fn][r] = acc2[fn][r] + part[0][row][n] + part[1][row][n]
                          + part[2][row][n] + bn + Af[(size_t)m * DM + n];
            }
        }
        float ps[4], pq[4];
        #pragma unroll
        for (int r = 0; r < 4; ++r) {
            float s = 0.f, q2 = 0.f;
            #pragma unroll
            for (int fn = 0; fn < 4; ++fn) { s += vv[fn][r]; q2 += vv[fn][r] * vv[fn][r]; }
            #pragma unroll
            for (int off = 1; off < 16; off <<= 1) {
                s += __shfl_xor(s, off);
                q2 += __shfl_xor(q2, off);
            }
            ps[r] = s; pq[r] = q2;
        }
        if (qi == 0) {
            #pragma unroll
            for (int r = 0; r < 4; ++r) {
                smean[ch][gq * 4 + r] = ps[r];
                ssq[ch][gq * 4 + r] = pq[r];
            }
        }
    }
    __syncthreads();

    if (kh == 0) {
        #pragma unroll
        for (int r = 0; r < 4; ++r) {
            const int row = gq * 4 + r;
            const int m = m0 + row;
            const float mean = (smean[0][row] + smean[1][row]) * (1.f / DM);
            const float var = (ssq[0][row] + ssq[1][row]) * (1.f / DM) - mean * mean;
            const float rstd = rsqrtf(var + EPS_LN);
            #pragma unroll
            for (int fn = 0; fn < 4; ++fn) {
                const int n = ch * 64 + fn * 16 + qi;
                outF[(size_t)m * DM + n] = (vv[fn][r] - mean) * rstd * lg[n] + lb[n];
            }
        }
    }
}

// ---------------------------------------------------------------------------
// Host-side orchestration (9 launches)
// ---------------------------------------------------------------------------
extern "C" void kernel_launch(void* const* d_in, const int* in_sizes, int n_in,
                              void* d_out, int out_size, void* d_ws, size_t ws_size,
                              hipStream_t stream)
{
    const float* x     = (const float*)d_in[0];
    const float* enc   = (const float*)d_in[1];
    const float* sa_wq = (const float*)d_in[2];
    const float* sa_bq = (const float*)d_in[3];
    const float* sa_wk = (const float*)d_in[4];
    const float* sa_bk = (const float*)d_in[5];
    const float* sa_wv = (const float*)d_in[6];
    const float* sa_bv = (const float*)d_in[7];
    const float* sa_wo = (const float*)d_in[8];
    const float* sa_bo = (const float*)d_in[9];
    const float* ln1_g = (const float*)d_in[10];
    const float* ln1_b = (const float*)d_in[11];
    const float* ca_wq = (const float*)d_in[12];
    const float* ca_bq = (const float*)d_in[13];
    const float* ca_wk = (const float*)d_in[14];
    const float* ca_bk = (const float*)d_in[15];
    const float* ca_wv = (const float*)d_in[16];
    const float* ca_bv = (const float*)d_in[17];
    const float* ca_wo = (const float*)d_in[18];
    const float* ca_bo = (const float*)d_in[19];
    const float* ln2_g = (const float*)d_in[20];
    const float* ln2_b = (const float*)d_in[21];
    const float* fc1_w = (const float*)d_in[22];
    const float* fc1_b = (const float*)d_in[23];
    const float* fc2_w = (const float*)d_in[24];
    const float* fc2_b = (const float*)d_in[25];
    const float* ln3_g = (const float*)d_in[26];
    const float* ln3_b = (const float*)d_in[27];

    float* out = (float*)d_out;
    char* ws = (char*)d_ws;

    const size_t NE = (size_t)ROWS * DM;        // 524288
    float* b5   = (float*)ws;    ws += NE * 4;
    float* b6   = (float*)ws;    ws += NE * 4;
    float* pacc = (float*)ws;    ws += (size_t)NBH * NQ32 * NC * PSTRIDE * 4; // ~17.8MB
    short* b3b  = (short*)ws;    ws += NE * 2;
    short* qh   = (short*)ws;    ws += NE * 2;
    short* kh   = (short*)ws;    ws += NE * 2 + 4096;
    short* vt   = (short*)ws;    ws += (size_t)NBH * VROWS * TT * 2 + 4096;   // 2MB + slack
    short* kh2  = (short*)ws;    ws += NE * 2 + 4096;
    short* vt2  = (short*)ws;    ws += (size_t)NBH * VROWS * TT * 2 + 4096;
    short* wt_saq = (short*)ws;  ws += DM * DM * 2;
    short* wt_sak = (short*)ws;  ws += DM * DM * 2;
    short* wt_sav = (short*)ws;  ws += DM * DM * 2;
    short* wt_sao = (short*)ws;  ws += DM * DM * 2;
    short* wt_caq = (short*)ws;  ws += DM * DM * 2;
    short* wt_cak = (short*)ws;  ws += DM * DM * 2;
    short* wt_cav = (short*)ws;  ws += DM * DM * 2;
    short* wt_cao = (short*)ws;  ws += DM * DM * 2;
    short* wt_fc1 = (short*)ws;  ws += DM * FFN_N * 2;
    short* wt_fc2 = (short*)ws;  ws += FFN_N * DM * 2;

    // Dh^-0.5 * log2(e): fold exp->exp2 into Q projections
    const float qscale = 0.25f * 1.4426950408889634f;
    const dim3 qkvgrid(DM / 64, ROWS / 64, 4);  // 512 blocks (2/CU)
    const dim3 partgrid(NBH * NQP * NC / 4);    // 1024 blocks
    const dim3 mergegrid(NBH * NQ32 / 4);       // 256 blocks
    const dim3 lngrid(ROWS / 16);               // 256 blocks

    // 1. weights (+ Vt ones-row init)
    hipLaunchKernelGGL(cvt_w_all, dim3(384), dim3(256), 0, stream,
                       sa_wq, sa_wk, sa_wv, sa_wo, ca_wq, ca_wk, ca_wv, ca_wo, fc1_w, fc2_w,
                       wt_saq, wt_sak, wt_sav, wt_sao, wt_caq, wt_cak, wt_cav, wt_cao, wt_fc1, wt_fc2,
                       vt, vt2);
    // 2. all x/enc-dependent projections
    hipLaunchKernelGGL(qkv_fused, qkvgrid, dim3(256), 0, stream,
                       x, enc, wt_saq, wt_sak, wt_sav, wt_cak, wt_cav,
                       sa_bq, sa_bk, sa_bv, ca_bk, ca_bv,
                       qh, kh, vt, kh2, vt2, qscale);
    // 3-4. self-attention
    hipLaunchKernelGGL((attn_part<1>), partgrid, dim3(256), 0, stream,
                       qh, kh, vt, pacc);
    hipLaunchKernelGGL(attn_merge, mergegrid, dim3(256), 0, stream, pacc, b3b, 1);
    // 5. o-proj + LN1 + cross-Q projection
    hipLaunchKernelGGL((lngemm<4, 1>), lngrid, dim3(256), 0, stream,
                       b3b, wt_sao, sa_bo, x, ln1_g, ln1_b, b5,
                       wt_caq, ca_bq, qh, qscale);
    // 6-7. cross-attention
    hipLaunchKernelGGL((attn_part<0>), partgrid, dim3(256), 0, stream,
                       qh, kh2, vt2, pacc);
    hipLaunchKernelGGL(attn_merge, mergegrid, dim3(256), 0, stream, pacc, b3b, 0);
    // 8. o-proj + LN2
    hipLaunchKernelGGL((lngemm<4, 0>), lngrid, dim3(256), 0, stream,
                       b3b, wt_cao, ca_bo, b5, ln2_g, ln2_b, b6,
                       (const short*)nullptr, (const float*)nullptr, (short*)nullptr, 1.f);
    // 9. FFN: fc1 + gelu + fc2 + LN3 -> out
    hipLaunchKernelGGL(ffn_fused, lngrid, dim3(512), 0, stream,
                       b6, wt_fc1, fc1_b, wt_fc2, fc2_b, ln3_g, ln3_b, out);
}

// Round 18
// 124.283 us; speedup vs baseline: 1.1414x; 1.1414x over previous
//
#include <hip/hip_runtime.h>
#include <hip/hip_bf16.h>

// Problem constants
#define TT 2048
#define BB 2
#define DM 128
#define HH 8
#define DH 16
#define FFN_N 1024
#define ROWS (TT * BB)
#define EPS_LN 1e-5f
#define NC 8              // s-chunks
#define SC (TT / NC)      // 256
#define NQ32 (TT / 32)    // 64 q-tiles of 32 per (b,h)
#define NQP (TT / 64)     // 32 q-PAIRS per (b,h)
#define NBH (BB * HH)     // 16
#define VROWS 32          // Vt rows per bh (16 data + row16=ones + 15 pad)
#define PSTRIDE 544       // pacc floats per task: 17 rows x 32 q

typedef __attribute__((ext_vector_type(8))) short bf16x8;
typedef __attribute__((ext_vector_type(4))) short bf16x4v;
typedef __attribute__((ext_vector_type(4))) float f32x4;
typedef __attribute__((ext_vector_type(16))) float f32x16;

__device__ __forceinline__ short f2bf(float x) {
    __hip_bfloat16 h = __float2bfloat16(x);
    union { __hip_bfloat16 hh; short s; } u; u.hh = h; return u.s;
}

// ---------------------------------------------------------------------------
// Fused weight convert+transpose: 10 weights f32 [K][N] -> bf16 [N][K].
// Also initializes Vt row 16 (per bh) to 1.0 bf16 for the ones-column trick.
// ---------------------------------------------------------------------------
__global__ __launch_bounds__(256) void cvt_w_all(
    const float* w0, const float* w1, const float* w2, const float* w3,
    const float* w4, const float* w5, const float* w6, const float* w7,
    const float* w8, const float* w9,
    short* o0, short* o1, short* o2, short* o3,
    short* o4, short* o5, short* o6, short* o7,
    short* o8, short* o9,
    short* vt1, short* vt2)
{
    // ones-row init: 2 tensors x NBH x TT = 65536 writes
    {
        const int id = blockIdx.x * 256 + threadIdx.x;
        if (id < 2 * NBH * TT) {
            const int sel = id / (NBH * TT);
            const int rem = id % (NBH * TT);
            const int bh = rem / TT, t = rem % TT;
            short* p = sel ? vt2 : vt1;
            p[((size_t)bh * VROWS + 16) * TT + t] = (short)0x3F80;
        }
    }

    const float* srcs[10] = {w0, w1, w2, w3, w4, w5, w6, w7, w8, w9};
    short* dsts[10] = {o0, o1, o2, o3, o4, o5, o6, o7, o8, o9};
    const int bx = blockIdx.x;
    int wi, tile, K, N;
    if (bx < 128)      { wi = bx >> 4; tile = bx & 15;  K = 128;  N = 128;  }
    else if (bx < 256) { wi = 8;       tile = bx - 128; K = 128;  N = 1024; }
    else               { wi = 9;       tile = bx - 256; K = 1024; N = 128;  }
    const float* src = srcs[wi];
    short* dst = dsts[wi];
    const int ntx = N >> 5;
    const int k0 = (tile / ntx) << 5;
    const int n0 = (tile % ntx) << 5;

    __shared__ float sm[32][33];
    const int j = threadIdx.x & 31;
    const int i0 = threadIdx.x >> 5;
    #pragma unroll
    for (int p = 0; p < 4; ++p) {
        const int ii = i0 + p * 8;
        sm[ii][j] = src[(size_t)(k0 + ii) * N + n0 + j];
    }
    __syncthreads();
    #pragma unroll
    for (int p = 0; p < 4; ++p) {
        const int ii = i0 + p * 8;
        dst[(size_t)(n0 + ii) * K + k0 + j] = f2bf(sm[j][ii]);
    }
}

// ---------------------------------------------------------------------------
// Fused QKV projection, 2 src-planes (z=0: x -> Q,K,V_sa; z=1: enc -> K,V_ca).
// Each block loops over its src's weights, reusing the A-tile via L1/L2.
// V^T rows stride VROWS=32 per bh (rows 0..15 written; row 16 = ones).
// ---------------------------------------------------------------------------
__global__ __launch_bounds__(256) void qkv_fused(
    const float* __restrict__ x, const float* __restrict__ enc,
    const short* __restrict__ W0, const short* __restrict__ W1, const short* __restrict__ W2,
    const short* __restrict__ W3, const short* __restrict__ W4,
    const float* __restrict__ B0, const float* __restrict__ B1, const float* __restrict__ B2,
    const float* __restrict__ B3, const float* __restrict__ B4,
    short* __restrict__ O0, short* __restrict__ O1, short* __restrict__ O2,
    short* __restrict__ O3, short* __restrict__ O4, float s0)
{
    const int src = blockIdx.z;
    const float* A = src ? enc : x;
    const int nw = src ? 2 : 3;
    const int K = DM, N = DM;

    const int tid = threadIdx.x;
    const int w = tid >> 6, lane = tid & 63;
    const int wm = w >> 1, wn = w & 1;
    const int g = lane >> 4, qi = lane & 15;
    const int bm = blockIdx.y * 64 + wm * 32;
    const int bn = blockIdx.x * 64 + wn * 32;

    for (int wsel = 0; wsel < nw; ++wsel) {
        const int z = src ? (3 + wsel) : wsel;
        const short* Wt = (z == 0) ? W0 : (z == 1) ? W1 : (z == 2) ? W2 : (z == 3) ? W3 : W4;
        const float* bias = (z == 0) ? B0 : (z == 1) ? B1 : (z == 2) ? B2 : (z == 3) ? B3 : B4;
        short* out = (z == 0) ? O0 : (z == 1) ? O1 : (z == 2) ? O2 : (z == 3) ? O3 : O4;
        const float scale = (z == 0) ? s0 : 1.f;
        const int vmode = (z == 2 || z == 4);

        f32x4 acc[2][2];
        #pragma unroll
        for (int a = 0; a < 2; ++a)
            #pragma unroll
            for (int b = 0; b < 2; ++b) acc[a][b] = (f32x4){0.f, 0.f, 0.f, 0.f};

        for (int k0 = 0; k0 < K; k0 += 32) {
            bf16x8 af[2], bf[2];
            #pragma unroll
            for (int fm = 0; fm < 2; ++fm) {
                const float* p = A + (size_t)(bm + fm * 16 + qi) * K + k0 + g * 4;
                float4 lo = *(const float4*)p;
                float4 hi = *(const float4*)(p + 16);
                af[fm][0] = f2bf(lo.x); af[fm][1] = f2bf(lo.y); af[fm][2] = f2bf(lo.z); af[fm][3] = f2bf(lo.w);
                af[fm][4] = f2bf(hi.x); af[fm][5] = f2bf(hi.y); af[fm][6] = f2bf(hi.z); af[fm][7] = f2bf(hi.w);
            }
            #pragma unroll
            for (int fn = 0; fn < 2; ++fn) {
                const short* p = Wt + (size_t)(bn + fn * 16 + qi) * K + k0 + g * 4;
                bf16x4v lo = *(const bf16x4v*)p;
                bf16x4v hi = *(const bf16x4v*)(p + 16);
                bf[fn][0] = lo[0]; bf[fn][1] = lo[1]; bf[fn][2] = lo[2]; bf[fn][3] = lo[3];
                bf[fn][4] = hi[0]; bf[fn][5] = hi[1]; bf[fn][6] = hi[2]; bf[fn][7] = hi[3];
            }
            #pragma unroll
            for (int fm = 0; fm < 2; ++fm)
                #pragma unroll
                for (int fn = 0; fn < 2; ++fn)
                    acc[fm][fn] = __builtin_amdgcn_mfma_f32_16x16x32_bf16(
                        af[fm], bf[fn], acc[fm][fn], 0, 0, 0);
        }

        #pragma unroll
        for (int fm = 0; fm < 2; ++fm)
            #pragma unroll
            for (int fn = 0; fn < 2; ++fn)
                #pragma unroll
                for (int r = 0; r < 4; ++r) {
                    const int m = bm + fm * 16 + g * 4 + r;
                    const int n = bn + fn * 16 + qi;
                    const float v = (acc[fm][fn][r] + bias[n]) * scale;
                    const int t = m >> 1, bz = m & 1, hH = n >> 4, d = n & 15;
                    size_t idx;
                    if (!vmode) {
                        const int dp = ((d >> 2) & 1) * 8 + (d & 3) + ((d >> 3) & 1) * 4;
                        idx = ((size_t)(bz * HH + hH) * TT + t) * DH + dp;
                    } else {
                        const int u = t & 15;
                        const int tp = (t & ~15) | (((u >> 2) & 1) * 8 + (u & 3) + ((u >> 3) & 1) * 4);
                        idx = ((size_t)(bz * HH + hH) * VROWS + d) * TT + tp;
                    }
                    out[idx] = f2bf(v);
                }
    }
}

// ---------------------------------------------------------------------------
// Flash attention PARTIAL. 32x32x16 MFMA, static-max softmax, exp2-folded,
// paired q-tiles, ones-column trick (Vt row 16 = 1.0 -> PV col 16 = L).
// launch_bounds(256,4): r17 showed (256,6) spills (2x f32x16 acc + scores).
// ---------------------------------------------------------------------------
template<int CAUSAL>
__global__ __launch_bounds__(256, 4) void attn_part(
    const short* __restrict__ Qh, const short* __restrict__ Kh,
    const short* __restrict__ Vt, float* __restrict__ pacc)
{
    const int wv = threadIdx.x >> 6;
    const int lane = threadIdx.x & 63;
    const int tsk = blockIdx.x * 4 + wv;        // ((bh*NQP + qp)*NC + c)
    const int bh = tsk >> 8;                    // /(NQP*NC)=256
    const int rr = tsk & 255;
    const int c = rr & (NC - 1);
    const int qp0 = rr >> 3;
    const int qp = (qp0 * 13 + c * 5) & (NQP - 1);   // bijective scramble
    const int qtA = qp * 64;
    const int qtB = qtA + 32;
    const int start = c * SC;
    const int send = CAUSAL ? min(start + SC, qtB + 32) : (start + SC);
    if (CAUSAL && start >= send) return;

    const int q = lane & 31;
    const int h = lane >> 5;

    const bf16x8 qf1 = *(const bf16x8*)(Qh + ((size_t)bh * TT + qtA + q) * DH + h * 8);
    const bf16x8 qf2 = *(const bf16x8*)(Qh + ((size_t)bh * TT + qtB + q) * DH + h * 8);

    f32x16 acc1, acc2;
    #pragma unroll
    for (int i = 0; i < 16; ++i) { acc1[i] = 0.f; acc2[i] = 0.f; }

    for (int sb = start; sb < send; sb += 32) {
        const bf16x8 kf = *(const bf16x8*)(Kh + ((size_t)bh * TT + sb + q) * DH + h * 8);
        f32x16 z;
        #pragma unroll
        for (int i = 0; i < 16; ++i) z[i] = 0.f;
        f32x16 s1 = __builtin_amdgcn_mfma_f32_32x32x16_bf16(kf, qf1, z, 0, 0, 0);
        f32x16 s2 = __builtin_amdgcn_mfma_f32_32x32x16_bf16(kf, qf2, z, 0, 0, 0);

        if (CAUSAL && (sb + 31 > qtA)) {
            #pragma unroll
            for (int r = 0; r < 16; ++r) {
                const int s_glob = sb + (r & 3) + 8 * (r >> 2) + 4 * h;
                if (s_glob > qtA + q) s1[r] = -1.0e30f;
                if (s_glob > qtB + q) s2[r] = -1.0e30f;
            }
        }

        #pragma unroll
        for (int i = 0; i < 16; ++i) {
            s1[i] = exp2f(s1[i]);
            s2[i] = exp2f(s2[i]);
        }

        #pragma unroll
        for (int j = 0; j < 2; ++j) {
            bf16x8 pf1, pf2;
            #pragma unroll
            for (int e = 0; e < 8; ++e) { pf1[e] = f2bf(s1[8 * j + e]); pf2[e] = f2bf(s2[8 * j + e]); }
            const bf16x8 vf = *(const bf16x8*)(Vt + ((size_t)bh * VROWS + q) * TT + sb + 16 * j + h * 8);
            acc1 = __builtin_amdgcn_mfma_f32_32x32x16_bf16(pf1, vf, acc1, 0, 0, 0);
            acc2 = __builtin_amdgcn_mfma_f32_32x32x16_bf16(pf2, vf, acc2, 0, 0, 0);
        }
    }

    const size_t tA = ((size_t)bh * NQ32 + qp * 2) * NC + c;
    const size_t tB = ((size_t)bh * NQ32 + qp * 2 + 1) * NC + c;
    const int d = q;
    if (d < 17) {                     // rows 0..15 = O partials, row 16 = L
        float* pb1 = pacc + tA * PSTRIDE + (size_t)d * 32;
        float* pb2 = pacc + tB * PSTRIDE + (size_t)d * 32;
        *(f32x4*)(pb1 + 4 * h)      = (f32x4){acc1[0],  acc1[1],  acc1[2],  acc1[3]};
        *(f32x4*)(pb1 + 8 + 4 * h)  = (f32x4){acc1[4],  acc1[5],  acc1[6],  acc1[7]};
        *(f32x4*)(pb1 + 16 + 4 * h) = (f32x4){acc1[8],  acc1[9],  acc1[10], acc1[11]};
        *(f32x4*)(pb1 + 24 + 4 * h) = (f32x4){acc1[12], acc1[13], acc1[14], acc1[15]};
        *(f32x4*)(pb2 + 4 * h)      = (f32x4){acc2[0],  acc2[1],  acc2[2],  acc2[3]};
        *(f32x4*)(pb2 + 8 + 4 * h)  = (f32x4){acc2[4],  acc2[5],  acc2[6],  acc2[7]};
        *(f32x4*)(pb2 + 16 + 4 * h) = (f32x4){acc2[8],  acc2[9],  acc2[10], acc2[11]};
        *(f32x4*)(pb2 + 24 + 4 * h) = (f32x4){acc2[12], acc2[13], acc2[14], acc2[15]};
    }
}

// ---------------------------------------------------------------------------
// Flash attention MERGE (static-max: plain sums; L = pacc row 16).
// One wave per (bh, qt32).
// ---------------------------------------------------------------------------
__global__ __launch_bounds__(256) void attn_merge(
    const float* __restrict__ pacc, short* __restrict__ outb, int causal)
{
    const int wv = threadIdx.x >> 6;
    const int lane = threadIdx.x & 63;
    const int task2 = blockIdx.x * 4 + wv;    // bh*NQ32 + qt32
    const int qt32 = task2 & (NQ32 - 1);
    const int bh = task2 >> 6;
    const int bz = bh / HH, head = bh % HH;
    const int qt = qt32 * 32;
    const int q = lane & 31, h = lane >> 5;
    const int qp = qt32 >> 1;
    const int nc = causal ? min(NC, (qp * 64 + 64 + SC - 1) / SC) : NC;
    const size_t base = (size_t)task2 * NC;

    float L = 0.f;
    float o[8] = {0.f, 0.f, 0.f, 0.f, 0.f, 0.f, 0.f, 0.f};
    for (int c = 0; c < nc; ++c) {
        const float* pb = pacc + (base + c) * PSTRIDE;
        L += pb[16 * 32 + q];
        const float* pr = pb + (size_t)h * 8 * 32 + q;
        #pragma unroll
        for (int dd = 0; dd < 8; ++dd) o[dd] += pr[dd * 32];
    }

    const float inv = 1.f / L;
    short* op = outb + ((size_t)(qt + q) * BB + bz) * DM + head * DH + h * 8;
    bf16x8 ov;
    #pragma unroll
    for (int dd = 0; dd < 8; ++dd) ov[dd] = f2bf(o[dd] * inv);
    *(bf16x8*)op = ov;
}

// ---------------------------------------------------------------------------
// Fused GEMM(+bias+resid)+LayerNorm, 256 threads = 4 waves (r11-verified).
// QPROJ=1 additionally computes the cross-attn Q projection of the LN output.
// ---------------------------------------------------------------------------
template<int KSTEPS, int QPROJ>
__global__ __launch_bounds__(256) void lngemm(
    const short* __restrict__ A, const short* __restrict__ Wt,
    const float* __restrict__ bias, const float* __restrict__ resid,
    const float* __restrict__ lg, const float* __restrict__ lb,
    float* __restrict__ outF,
    const short* __restrict__ Wq, const float* __restrict__ bq,
    short* __restrict__ Oq, float qs)
{
    const int tid = threadIdx.x;
    const int w = tid >> 6;
    const int lane = tid & 63;
    const int ch = w & 1, kh = w >> 1;
    const int gq = lane >> 4, qi = lane & 15;
    const int m0 = blockIdx.x * 16;
    const int K = KSTEPS * 32;
    const int KH = KSTEPS / 2;

    __shared__ float part[16][130];
    __shared__ float smean[2][16], ssq[2][16];
    __shared__ short Alds[16][136];

    f32x4 acc[4];
    #pragma unroll
    for (int fn = 0; fn < 4; ++fn) acc[fn] = (f32x4){0.f, 0.f, 0.f, 0.f};

    for (int ks = kh * KH; ks < kh * KH + KH; ++ks) {
        const int k0 = ks * 32;
        bf16x8 af;
        {
            const short* p = A + (size_t)(m0 + qi) * K + k0 + gq * 4;
            bf16x4v lo = *(const bf16x4v*)p;
            bf16x4v hi = *(const bf16x4v*)(p + 16);
            af[0] = lo[0]; af[1] = lo[1]; af[2] = lo[2]; af[3] = lo[3];
            af[4] = hi[0]; af[5] = hi[1]; af[6] = hi[2]; af[7] = hi[3];
        }
        #pragma unroll
        for (int fn = 0; fn < 4; ++fn) {
            const short* p = Wt + (size_t)(ch * 64 + fn * 16 + qi) * K + k0 + gq * 4;
            bf16x4v lo = *(const bf16x4v*)p;
            bf16x4v hi = *(const bf16x4v*)(p + 16);
            bf16x8 bf;
            bf[0] = lo[0]; bf[1] = lo[1]; bf[2] = lo[2]; bf[3] = lo[3];
            bf[4] = hi[0]; bf[5] = hi[1]; bf[6] = hi[2]; bf[7] = hi[3];
            acc[fn] = __builtin_amdgcn_mfma_f32_16x16x32_bf16(af, bf, acc[fn], 0, 0, 0);
        }
    }

    if (kh == 1) {
        #pragma unroll
        for (int fn = 0; fn < 4; ++fn)
            #pragma unroll
            for (int r = 0; r < 4; ++r)
                part[gq * 4 + r][ch * 64 + fn * 16 + qi] = acc[fn][r];
    }
    __syncthreads();

    float vv[4][4];
    if (kh == 0) {
        #pragma unroll
        for (int fn = 0; fn < 4; ++fn) {
            const int n = ch * 64 + fn * 16 + qi;
            const float bn = bias[n];
            #pragma unroll
            for (int r = 0; r < 4; ++r) {
                const int m = m0 + gq * 4 + r;
                vv[fn][r] = acc[fn][r] + part[gq * 4 + r][n] + bn
                          + resid[(size_t)m * DM + n];
            }
        }
        float ps[4], pq[4];
        #pragma unroll
        for (int r = 0; r < 4; ++r) {
            float s = 0.f, q2 = 0.f;
            #pragma unroll
            for (int fn = 0; fn < 4; ++fn) { s += vv[fn][r]; q2 += vv[fn][r] * vv[fn][r]; }
            #pragma unroll
            for (int off = 1; off < 16; off <<= 1) {
                s += __shfl_xor(s, off);
                q2 += __shfl_xor(q2, off);
            }
            ps[r] = s; pq[r] = q2;
        }
        if (qi == 0) {
            #pragma unroll
            for (int r = 0; r < 4; ++r) {
                smean[ch][gq * 4 + r] = ps[r];
                ssq[ch][gq * 4 + r] = pq[r];
            }
        }
    }
    __syncthreads();

    if (kh == 0) {
        #pragma unroll
        for (int r = 0; r < 4; ++r) {
            const int row = gq * 4 + r;
            const int m = m0 + row;
            const float mean = (smean[0][row] + smean[1][row]) * (1.f / DM);
            const float var = (ssq[0][row] + ssq[1][row]) * (1.f / DM) - mean * mean;
            const float rstd = rsqrtf(var + EPS_LN);
            #pragma unroll
            for (int fn = 0; fn < 4; ++fn) {
                const int n = ch * 64 + fn * 16 + qi;
                const float val = (vv[fn][r] - mean) * rstd * lg[n] + lb[n];
                outF[(size_t)m * DM + n] = val;
                if (QPROJ) Alds[row][n] = f2bf(val);
            }
        }
    }

    if (QPROJ) {
        __syncthreads();
        f32x4 qacc[2];
        qacc[0] = (f32x4){0.f, 0.f, 0.f, 0.f};
        qacc[1] = (f32x4){0.f, 0.f, 0.f, 0.f};
        for (int ks = 0; ks < 4; ++ks) {
            const int k0 = ks * 32;
            bf16x8 af;
            {
                const short* p = &Alds[qi][k0 + gq * 4];
                af[0] = p[0]; af[1] = p[1]; af[2] = p[2]; af[3] = p[3];
                af[4] = p[16]; af[5] = p[17]; af[6] = p[18]; af[7] = p[19];
            }
            #pragma unroll
            for (int fn = 0; fn < 2; ++fn) {
                const short* p = Wq + (size_t)(w * 32 + fn * 16 + qi) * DM + k0 + gq * 4;
                bf16x4v lo = *(const bf16x4v*)p;
                bf16x4v hi = *(const bf16x4v*)(p + 16);
                bf16x8 bf;
                bf[0] = lo[0]; bf[1] = lo[1]; bf[2] = lo[2]; bf[3] = lo[3];
                bf[4] = hi[0]; bf[5] = hi[1]; bf[6] = hi[2]; bf[7] = hi[3];
                qacc[fn] = __builtin_amdgcn_mfma_f32_16x16x32_bf16(af, bf, qacc[fn], 0, 0, 0);
            }
        }
        #pragma unroll
        for (int fn = 0; fn < 2; ++fn)
            #pragma unroll
            for (int r = 0; r < 4; ++r) {
                const int m = m0 + gq * 4 + r;
                const int n = w * 32 + fn * 16 + qi;
                const float v = (qacc[fn][r] + bq[n]) * qs;
                const int t = m >> 1, bz = m & 1, hH = n >> 4, d = n & 15;
                const int dp = ((d >> 2) & 1) * 8 + (d & 3) + ((d >> 3) & 1) * 4;
                Oq[((size_t)(bz * HH + hH) * TT + t) * DH + dp] = f2bf(v);
            }
    }
}

// ---------------------------------------------------------------------------
// Fused FFN: fc1+gelu (-> LDS) + fc2 + LN3 -> out. Block = 16 rows, 512 thr.
// ---------------------------------------------------------------------------
__global__ __launch_bounds__(512) void ffn_fused(
    const float* __restrict__ Af,    // b6 f32 [ROWS][DM] (also the residual)
    const short* __restrict__ W1t, const float* __restrict__ b1,
    const short* __restrict__ W2t, const float* __restrict__ b2,
    const float* __restrict__ lg, const float* __restrict__ lb,
    float* __restrict__ outF)
{
    const int tid = threadIdx.x;
    const int w = tid >> 6, lane = tid & 63;
    const int gq = lane >> 4, qi = lane & 15;
    const int m0 = blockIdx.x * 16;

    __shared__ short hlds[16][1032];
    __shared__ float part[3][16][130];
    __shared__ float smean[2][16], ssq[2][16];

    // ---- phase 1: fc1 + gelu ----
    {
        f32x4 acc[8];
        #pragma unroll
        for (int fn = 0; fn < 8; ++fn) acc[fn] = (f32x4){0.f, 0.f, 0.f, 0.f};
        for (int ks = 0; ks < 4; ++ks) {
            const int k0 = ks * 32;
            bf16x8 af;
            {
                const float* p = Af + (size_t)(m0 + qi) * DM + k0 + gq * 4;
                float4 lo = *(const float4*)p;
                float4 hi = *(const float4*)(p + 16);
                af[0] = f2bf(lo.x); af[1] = f2bf(lo.y); af[2] = f2bf(lo.z); af[3] = f2bf(lo.w);
                af[4] = f2bf(hi.x); af[5] = f2bf(hi.y); af[6] = f2bf(hi.z); af[7] = f2bf(hi.w);
            }
            #pragma unroll
            for (int fn = 0; fn < 8; ++fn) {
                const short* p = W1t + (size_t)(w * 128 + fn * 16 + qi) * DM + k0 + gq * 4;
                bf16x4v lo = *(const bf16x4v*)p;
                bf16x4v hi = *(const bf16x4v*)(p + 16);
                bf16x8 bf;
                bf[0] = lo[0]; bf[1] = lo[1]; bf[2] = lo[2]; bf[3] = lo[3];
                bf[4] = hi[0]; bf[5] = hi[1]; bf[6] = hi[2]; bf[7] = hi[3];
                acc[fn] = __builtin_amdgcn_mfma_f32_16x16x32_bf16(af, bf, acc[fn], 0, 0, 0);
            }
        }
        #pragma unroll
        for (int fn = 0; fn < 8; ++fn) {
            const int n = w * 128 + fn * 16 + qi;
            const float bn = b1[n];
            #pragma unroll
            for (int r = 0; r < 4; ++r) {
                float v = acc[fn][r] + bn;
                v = 0.5f * v * (1.f + erff(v * 0.70710678118654752f));
                hlds[gq * 4 + r][n] = f2bf(v);
            }
        }
    }
    __syncthreads();

    // ---- phase 2: fc2 + LN3 ----
    const int ch = w & 1, kh = w >> 1;   // kh 0..3

    f32x4 acc2[4];
    #pragma unroll
    for (int fn = 0; fn < 4; ++fn) acc2[fn] = (f32x4){0.f, 0.f, 0.f, 0.f};

    for (int ks = kh * 8; ks < kh * 8 + 8; ++ks) {
        const int k0 = ks * 32;
        bf16x8 af;
        {
            const short* p = &hlds[qi][k0 + gq * 4];
            af[0] = p[0]; af[1] = p[1]; af[2] = p[2]; af[3] = p[3];
            af[4] = p[16]; af[5] = p[17]; af[6] = p[18]; af[7] = p[19];
        }
        #pragma unroll
        for (int fn = 0; fn < 4; ++fn) {
            const short* p = W2t + (size_t)(ch * 64 + fn * 16 + qi) * FFN_N + k0 + gq * 4;
            bf16x4v lo = *(const bf16x4v*)p;
            bf16x4v hi = *(const bf16x4v*)(p + 16);
            bf16x8 bf;
            bf[0] = lo[0]; bf[1] = lo[1]; bf[2] = lo[2]; bf[3] = lo[3];
            bf[4] = hi[0]; bf[5] = hi[1]; bf[6] = hi[2]; bf[7] = hi[3];
            acc2[fn] = __builtin_amdgcn_mfma_f32_16x16x32_bf16(af, bf, acc2[fn], 0, 0, 0);
        }
    }

    if (kh >= 1) {
        #pragma unroll
        for (int fn = 0; fn < 4; ++fn)
            #pragma unroll
            for (int r = 0; r < 4; ++r)
                part[kh - 1][gq * 4 + r][ch * 64 + fn * 16 + qi] = acc2[fn][r];
    }
    __syncthreads();

    float vv[4][4];
    if (kh == 0) {
        #pragma unroll
        for (int fn = 0; fn < 4; ++fn) {
            const int n = ch * 64 + fn * 16 + qi;
            const float bn = b2[n];
            #pragma unroll
            for (int r = 0; r < 4; ++r) {
                const int row = gq * 4 + r;
                const int m = m0 + row;
                vv[fn][r] = acc2[fn][r] + part[0][row][n] + part[1][row][n]
                          + part[2][row][n] + bn + Af[(size_t)m * DM + n];
            }
        }
        float ps[4], pq[4];
        #pragma unroll
        for (int r = 0; r < 4; ++r) {
            float s = 0.f, q2 = 0.f;
            #pragma unroll
            for (int fn = 0; fn < 4; ++fn) { s += vv[fn][r]; q2 += vv[fn][r] * vv[fn][r]; }
            #pragma unroll
            for (int off = 1; off < 16; off <<= 1) {
                s += __shfl_xor(s, off);
                q2 += __shfl_xor(q2, off);
            }
            ps[r] = s; pq[r] = q2;
        }
        if (qi == 0) {
            #pragma unroll
            for (int r = 0; r < 4; ++r) {
                smean[ch][gq * 4 + r] = ps[r];
                ssq[ch][gq * 4 + r] = pq[r];
            }
        }
    }
    __syncthreads();

    if (kh == 0) {
        #pragma unroll
        for (int r = 0; r < 4; ++r) {
            const int row = gq * 4 + r;
            const int m = m0 + row;
            const float mean = (smean[0][row] + smean[1][row]) * (1.f / DM);
            const float var = (ssq[0][row] + ssq[1][row]) * (1.f / DM) - mean * mean;
            const float rstd = rsqrtf(var + EPS_LN);
            #pragma unroll
            for (int fn = 0; fn < 4; ++fn) {
                const int n = ch * 64 + fn * 16 + qi;
                outF[(size_t)m * DM + n] = (vv[fn][r] - mean) * rstd * lg[n] + lb[n];
            }
        }
    }
}

// ---------------------------------------------------------------------------
// Host-side orchestration (9 launches)
// ---------------------------------------------------------------------------
extern "C" void kernel_launch(void* const* d_in, const int* in_sizes, int n_in,
                              void* d_out, int out_size, void* d_ws, size_t ws_size,
                              hipStream_t stream)
{
    const float* x     = (const float*)d_in[0];
    const float* enc   = (const float*)d_in[1];
    const float* sa_wq = (const float*)d_in[2];
    const float* sa_bq = (const float*)d_in[3];
    const float* sa_wk = (const float*)d_in[4];
    const float* sa_bk = (const float*)d_in[5];
    const float* sa_wv = (const float*)d_in[6];
    const float* sa_bv = (const float*)d_in[7];
    const float* sa_wo = (const float*)d_in[8];
    const float* sa_bo = (const float*)d_in[9];
    const float* ln1_g = (const float*)d_in[10];
    const float* ln1_b = (const float*)d_in[11];
    const float* ca_wq = (const float*)d_in[12];
    const float* ca_bq = (const float*)d_in[13];
    const float* ca_wk = (const float*)d_in[14];
    const float* ca_bk = (const float*)d_in[15];
    const float* ca_wv = (const float*)d_in[16];
    const float* ca_bv = (const float*)d_in[17];
    const float* ca_wo = (const float*)d_in[18];
    const float* ca_bo = (const float*)d_in[19];
    const float* ln2_g = (const float*)d_in[20];
    const float* ln2_b = (const float*)d_in[21];
    const float* fc1_w = (const float*)d_in[22];
    const float* fc1_b = (const float*)d_in[23];
    const float* fc2_w = (const float*)d_in[24];
    const float* fc2_b = (const float*)d_in[25];
    const float* ln3_g = (const float*)d_in[26];
    const float* ln3_b = (const float*)d_in[27];

    float* out = (float*)d_out;
    char* ws = (char*)d_ws;

    const size_t NE = (size_t)ROWS * DM;        // 524288
    float* b5   = (float*)ws;    ws += NE * 4;
    float* b6   = (float*)ws;    ws += NE * 4;
    float* pacc = (float*)ws;    ws += (size_t)NBH * NQ32 * NC * PSTRIDE * 4; // ~17.8MB
    short* b3b  = (short*)ws;    ws += NE * 2;
    short* qh   = (short*)ws;    ws += NE * 2;
    short* kh   = (short*)ws;    ws += NE * 2 + 4096;
    short* vt   = (short*)ws;    ws += (size_t)NBH * VROWS * TT * 2 + 4096;   // 2MB + slack
    short* kh2  = (short*)ws;    ws += NE * 2 + 4096;
    short* vt2  = (short*)ws;    ws += (size_t)NBH * VROWS * TT * 2 + 4096;
    short* wt_saq = (short*)ws;  ws += DM * DM * 2;
    short* wt_sak = (short*)ws;  ws += DM * DM * 2;
    short* wt_sav = (short*)ws;  ws += DM * DM * 2;
    short* wt_sao = (short*)ws;  ws += DM * DM * 2;
    short* wt_caq = (short*)ws;  ws += DM * DM * 2;
    short* wt_cak = (short*)ws;  ws += DM * DM * 2;
    short* wt_cav = (short*)ws;  ws += DM * DM * 2;
    short* wt_cao = (short*)ws;  ws += DM * DM * 2;
    short* wt_fc1 = (short*)ws;  ws += DM * FFN_N * 2;
    short* wt_fc2 = (short*)ws;  ws += FFN_N * DM * 2;

    // Dh^-0.5 * log2(e): fold exp->exp2 into Q projections
    const float qscale = 0.25f * 1.4426950408889634f;
    const dim3 qkvgrid(DM / 64, ROWS / 64, 2);  // 128 blocks x 2 src
    const dim3 partgrid(NBH * NQP * NC / 4);    // 1024 blocks
    const dim3 mergegrid(NBH * NQ32 / 4);       // 256 blocks
    const dim3 lngrid(ROWS / 16);               // 256 blocks

    // 1. weights (+ Vt ones-row init)
    hipLaunchKernelGGL(cvt_w_all, dim3(384), dim3(256), 0, stream,
                       sa_wq, sa_wk, sa_wv, sa_wo, ca_wq, ca_wk, ca_wv, ca_wo, fc1_w, fc2_w,
                       wt_saq, wt_sak, wt_sav, wt_sao, wt_caq, wt_cak, wt_cav, wt_cao, wt_fc1, wt_fc2,
                       vt, vt2);
    // 2. all x/enc-dependent projections
    hipLaunchKernelGGL(qkv_fused, qkvgrid, dim3(256), 0, stream,
                       x, enc, wt_saq, wt_sak, wt_sav, wt_cak, wt_cav,
                       sa_bq, sa_bk, sa_bv, ca_bk, ca_bv,
                       qh, kh, vt, kh2, vt2, qscale);
    // 3-4. self-attention
    hipLaunchKernelGGL((attn_part<1>), partgrid, dim3(256), 0, stream,
                       qh, kh, vt, pacc);
    hipLaunchKernelGGL(attn_merge, mergegrid, dim3(256), 0, stream, pacc, b3b, 1);
    // 5. o-proj + LN1 + cross-Q projection
    hipLaunchKernelGGL((lngemm<4, 1>), lngrid, dim3(256), 0, stream,
                       b3b, wt_sao, sa_bo, x, ln1_g, ln1_b, b5,
                       wt_caq, ca_bq, qh, qscale);
    // 6-7. cross-attention
    hipLaunchKernelGGL((attn_part<0>), partgrid, dim3(256), 0, stream,
                       qh, kh2, vt2, pacc);
    hipLaunchKernelGGL(attn_merge, mergegrid, dim3(256), 0, stream, pacc, b3b, 0);
    // 8. o-proj + LN2
    hipLaunchKernelGGL((lngemm<4, 0>), lngrid, dim3(256), 0, stream,
                       b3b, wt_cao, ca_bo, b5, ln2_g, ln2_b, b6,
                       (const short*)nullptr, (const float*)nullptr, (short*)nullptr, 1.f);
    // 9. FFN: fc1 + gelu + fc2 + LN3 -> out
    hipLaunchKernelGGL(ffn_fused, lngrid, dim3(512), 0, stream,
                       b6, wt_fc1, fc1_b, wt_fc2, fc2_b, ln3_g, ln3_b, out);
}